// Round 2
// 320.497 us; speedup vs baseline: 1.0215x; 1.0215x over previous
//
#include <hip/hip_runtime.h>

#define NN 100000
#define NE 600000
#define ET (NE + NN)
#define D 128
#define NREL 16
#define SCANB 391   // 391*256 = 100096 >= NN
#define TPB 4       // tiles per gemm block
#define MAXTILES 10954
#define GEMMG ((MAXTILES + TPB - 1) / TPB)
#define WGRID 1088  // 17*16384/256

typedef short short8 __attribute__((ext_vector_type(8)));
typedef float f32x4 __attribute__((ext_vector_type(4)));
typedef unsigned int u32x4 __attribute__((ext_vector_type(4)));

// meta layout (ints)
#define C0 0    // counts[17]
#define O0 20   // offsets[18]
#define CU0 40  // cursors[17]
#define T0 60   // tileoff[18]

// ws layout (bytes)
#define WT_OFF   0                 // 17*128*128 bf16 = 557056
#define META_OFF 557056            // 512
#define DH_OFF   557568            // dstHist: 100000 ints
#define DO_OFF   957568            // dstOff: 100001 ints
#define DC_OFF   1357576           // dstCursor: 100000 ints
#define BS_OFF   1757576           // blockSums: 391 ints (pad)
#define SCP_OFF  1759576           // sCP: 700064 int2
#define SR_OFF   7360088           // sRow (fallback only): 700000 ints
#define XB_OFF   10160096          // xb: 100000*128 bf16
#define MSGB_OFF 35760096          // msg (mode B)
#define MSGA_OFF 10160096          // msg (mode A, no xb)
#define NEED_B   (MSGB_OFF + (size_t)ET * 128 * 2)
#define NEED_A   (MSGA_OFF + (size_t)ET * 128 * 2)

__device__ __forceinline__ unsigned short f2bf(float f) {
  unsigned u = __builtin_bit_cast(unsigned, f);
  u += 0x7fffu + ((u >> 16) & 1u);   // RNE; inputs finite/normal
  return (unsigned short)(u >> 16);
}

// blockIdx < WGRID: wT[r][o][i] = sum_b coef[r,b]*bases[b][i][o]; slot16 = w_self.
// else: x fp32 -> xb bf16 (4 elems/thread).
__global__ __launch_bounds__(256) void k_prep(const float* __restrict__ bases,
    const float* __restrict__ coef, const float* __restrict__ w_self,
    unsigned short* __restrict__ wT, const float* __restrict__ x,
    unsigned short* __restrict__ xb)
{
  if (blockIdx.x < WGRID) {
    int idx = blockIdx.x * 256 + threadIdx.x;   // < 17*16384
    int r = idx >> 14;
    int t = idx & 16383;
    float v;
    if (r < 16) {
      int o = t >> 7, i = t & 127;
      float acc = 0.f;
      #pragma unroll
      for (int b = 0; b < 8; ++b)
        acc += coef[r * 8 + b] * bases[b * 16384 + i * 128 + o];
      v = acc;
    } else {
      v = w_self[t];
    }
    wT[idx] = f2bf(v);
  } else {
    int i = (blockIdx.x - WGRID) * 256 + threadIdx.x;
    if (i >= NN * D / 4) return;
    // x is read exactly once per iteration -> nontemporal (keep L3 for xb/wT)
    f32x4 f = __builtin_nontemporal_load((const f32x4*)(x + (size_t)i * 4));
    unsigned short s0 = f2bf(f[0]), s1 = f2bf(f[1]), s2 = f2bf(f[2]), s3 = f2bf(f[3]);
    unsigned long long pk = (unsigned long long)s0 | ((unsigned long long)s1 << 16)
                          | ((unsigned long long)s2 << 32) | ((unsigned long long)s3 << 48);
    *(unsigned long long*)(xb + (size_t)i * 4) = pk;   // cached: xb is the reuse set
  }
}

// rel histogram (LDS) + dst histogram (global atomics)
__global__ __launch_bounds__(256) void k_hist(const int* __restrict__ ei,
    const int* __restrict__ et, int* __restrict__ meta, int* __restrict__ dstHist)
{
  __shared__ int h[16];
  int tid = threadIdx.x;
  if (tid < 16) h[tid] = 0;
  __syncthreads();
  for (int e = blockIdx.x * 256 + tid; e < NE; e += gridDim.x * 256) {
    atomicAdd(&h[et[e]], 1);
    atomicAdd(&dstHist[ei[e]], 1);
  }
  __syncthreads();
  if (tid < 16) atomicAdd(&meta[C0 + tid], h[tid]);
}

__global__ __launch_bounds__(256) void k_scan1(const int* __restrict__ dstHist,
    int* __restrict__ dstOff, int* __restrict__ blockSums)
{
  __shared__ int sh[256];
  int tid = threadIdx.x;
  int d = blockIdx.x * 256 + tid;
  int v = (d < NN) ? (dstHist[d] + 1) : 0;   // +1: virtual self edge
  sh[tid] = v;
  __syncthreads();
  #pragma unroll
  for (int ofs = 1; ofs < 256; ofs <<= 1) {
    int t = (tid >= ofs) ? sh[tid - ofs] : 0;
    __syncthreads();
    sh[tid] += t;
    __syncthreads();
  }
  if (d < NN) dstOff[d] = sh[tid] - v;
  if (tid == 255) blockSums[blockIdx.x] = sh[tid];
}

__global__ __launch_bounds__(512) void k_scan2(int* __restrict__ blockSums, int* __restrict__ meta)
{
  __shared__ int sh[SCANB];
  int tid = threadIdx.x;
  if (tid < SCANB) sh[tid] = blockSums[tid];
  __syncthreads();
  if (tid == 0) {
    int run = 0;
    for (int i = 0; i < SCANB; ++i) { int c = sh[i]; sh[i] = run; run += c; }
    meta[C0 + 16] = NN;
    int off = 0, toff = 0;
    for (int r = 0; r <= 16; ++r) {
      meta[O0 + r] = off;
      meta[CU0 + r] = off;
      meta[T0 + r] = toff;
      int c = meta[C0 + r];
      off += c;
      toff += (c + 63) >> 6;
    }
    meta[O0 + 17] = off;
    meta[T0 + 17] = toff;
  }
  __syncthreads();
  if (tid < SCANB) blockSums[tid] = sh[tid];
}

__global__ __launch_bounds__(256) void k_scan3(int* __restrict__ dstOff,
    const int* __restrict__ blockSums, int* __restrict__ dstCursor,
    int2* __restrict__ sCP)
{
  int tid = threadIdx.x;
  int d = blockIdx.x * 256 + tid;
  int base = blockSums[blockIdx.x];
  if (d < NN) {
    int o = dstOff[d] + base;
    dstOff[d] = o;
    dstCursor[d] = o + 1;
    sCP[NE + d] = make_int2(d, o);
  }
  if (d == NN) dstOff[NN] = ET;
}

__global__ __launch_bounds__(256) void k_self0(int2* __restrict__ sCP, int* __restrict__ sRow)
{
  int n = blockIdx.x * 256 + threadIdx.x;
  if (n < NN) { sCP[NE + n] = make_int2(n, 0); sRow[NE + n] = n; }
}

__global__ __launch_bounds__(256) void k_scatter(const int* __restrict__ ei, const int* __restrict__ et,
    int* __restrict__ meta, int2* __restrict__ sCP, int* __restrict__ sRow,
    int* __restrict__ dstCursor, int doMsg)
{
  __shared__ int h[16], base[16], lh[16];
  int tid = threadIdx.x;
  int start = blockIdx.x * 4096;
  int end = min(NE, start + 4096);
  if (tid < 16) { h[tid] = 0; lh[tid] = 0; }
  __syncthreads();
  for (int e = start + tid; e < end; e += 256)
    atomicAdd(&h[et[e]], 1);
  __syncthreads();
  if (tid < 16) base[tid] = atomicAdd(&meta[CU0 + tid], h[tid]);
  __syncthreads();
  for (int e = start + tid; e < end; e += 256) {
    int r = et[e];
    int row = ei[e];
    int pos = base[r] + atomicAdd(&lh[r], 1);
    int slot = doMsg ? atomicAdd(&dstCursor[row], 1) : 0;
    sCP[pos] = make_int2(ei[NE + e], slot);
    if (!doMsg) sRow[pos] = row;
  }
}

// TPB tiles/block. Fast path (xbf&&msgmode): 2 barriers/tile, register prefetch
// of next tile's gather overlapping MFMA+epilogue. Generic fallback: R4 code.
// msg stores are nontemporal: stream-once, keep xb resident in L3.
__global__ __launch_bounds__(256) void k_gemm(const float* __restrict__ xf,
    const unsigned short* __restrict__ xb,
    const unsigned short* __restrict__ wT, const int* __restrict__ meta,
    const int2* __restrict__ sCP, const int* __restrict__ sRow,
    unsigned short* __restrict__ msg, float* __restrict__ out,
    int xbf, int msgmode)
{
  __shared__ short As[64 * 17 * 8];   // staging (8704 shorts; fallback reuses for transpose)
  __shared__ short Es[64 * 136];      // epilogue rows
  __shared__ int Pos2[2][64];
  __shared__ int Rows[64];
  __shared__ int Ms[80];

  int tid = threadIdx.x;
  if (tid < 80) Ms[tid] = meta[tid];
  __syncthreads();
  int ntiles = Ms[T0 + 17];

  int lane = tid & 63, wave = tid >> 6;
  int q = lane >> 4, l15 = lane & 15;
  int m = tid >> 2, ug = tid & 3;

  if (xbf && msgmode) {
    short8 pf[4];
    int pcy = 0;
    bool pvalid = false;
    int r = 0, nr = 0;
    int b = blockIdx.x * TPB;
    if (b < ntiles) {
      while (r < 16 && Ms[T0 + r + 1] <= b) ++r;
      int boff = Ms[O0 + r];
      int e0 = boff + (b - Ms[T0 + r]) * 64;
      nr = min(64, boff + Ms[C0 + r] - e0);
      pvalid = m < nr;
      int2 cp = sCP[pvalid ? (e0 + m) : e0];
      pcy = cp.y;
      const unsigned short* xr = xb + (size_t)cp.x * 128;
      #pragma unroll
      for (int s = 0; s < 4; ++s) {
        short8 v = (short8)(short)0;
        if (pvalid) v = *(const short8*)(xr + (ug * 4 + s) * 8);
        pf[s] = v;
      }
    }
    int rprev = -1;
    short8 bfr[2][4];
    for (int ti = 0; ti < TPB; ++ti) {
      b = blockIdx.x * TPB + ti;
      if (b >= ntiles) break;
      int curR = r, curNr = nr;
      // ---- staging store from prefetched regs ----
      #pragma unroll
      for (int s = 0; s < 4; ++s)
        *(short8*)&As[(m * 17 + ug * 4 + s) * 8] = pf[s];
      if (ug == 0) Pos2[ti & 1][m] = pvalid ? pcy : 0;
      __syncthreads();   // sync1: staging visible; drains prior Es/Pos reads
      // ---- prefetch next tile (overlaps MFMA+epilogue) ----
      int bn = b + 1;
      if (ti + 1 < TPB && bn < ntiles) {
        int rn = curR;
        while (rn < 16 && Ms[T0 + rn + 1] <= bn) ++rn;
        int boff = Ms[O0 + rn];
        int e0n = boff + (bn - Ms[T0 + rn]) * 64;
        int nrn = min(64, boff + Ms[C0 + rn] - e0n);
        pvalid = m < nrn;
        int2 cp = sCP[pvalid ? (e0n + m) : e0n];
        pcy = cp.y;
        const unsigned short* xr = xb + (size_t)cp.x * 128;
        #pragma unroll
        for (int s = 0; s < 4; ++s) {
          short8 v = (short8)(short)0;
          if (pvalid) v = *(const short8*)(xr + (ug * 4 + s) * 8);
          pf[s] = v;
        }
        r = rn; nr = nrn;
      }
      // ---- B frags (reload only on rel change) ----
      if (curR != rprev) {
        const unsigned short* wr = wT + curR * 16384;
        #pragma unroll
        for (int ns = 0; ns < 2; ++ns)
          #pragma unroll
          for (int kk = 0; kk < 4; ++kk)
            bfr[ns][kk] = *(const short8*)(wr + (wave * 32 + ns * 16 + l15) * 128 + kk * 32 + q * 8);
        rprev = curR;
      }
      // ---- MFMA ----
      f32x4 acc[4][2];
      #pragma unroll
      for (int ms = 0; ms < 4; ++ms)
        #pragma unroll
        for (int ns = 0; ns < 2; ++ns)
          acc[ms][ns] = (f32x4){0.f, 0.f, 0.f, 0.f};
      #pragma unroll
      for (int kk = 0; kk < 4; ++kk) {
        short8 af[4];
        #pragma unroll
        for (int ms = 0; ms < 4; ++ms)
          af[ms] = *(const short8*)&As[((ms * 16 + l15) * 17 + kk * 4 + q) * 8];
        #pragma unroll
        for (int ms = 0; ms < 4; ++ms)
          #pragma unroll
          for (int ns = 0; ns < 2; ++ns)
            acc[ms][ns] = __builtin_amdgcn_mfma_f32_16x16x32_bf16(af[ms], bfr[ns][kk], acc[ms][ns], 0, 0, 0);
      }
      // ---- transpose to Es ----
      #pragma unroll
      for (int ms = 0; ms < 4; ++ms)
        #pragma unroll
        for (int ns = 0; ns < 2; ++ns)
          #pragma unroll
          for (int reg = 0; reg < 4; ++reg)
            Es[(ms * 16 + q * 4 + reg) * 136 + wave * 32 + ns * 16 + l15] =
                (short)f2bf(acc[ms][ns][reg]);
      __syncthreads();   // sync2: Es visible; MFMA As-reads drained
      // ---- full-row msg stores (nontemporal: stream-once) ----
      #pragma unroll
      for (int i = 0; i < 4; ++i) {
        int row = wave * 16 + i * 4 + q;
        short8 v = *(const short8*)&Es[row * 136 + l15 * 8];
        if (row < curNr)
          __builtin_nontemporal_store(v,
              (short8*)(msg + (size_t)Pos2[ti & 1][row] * 128 + l15 * 8));
      }
    }
    return;
  }

  // ---------------- generic fallback (R4-validated) ----------------
  int rprev = -1;
  short8 bfr[2][4];
  for (int ti = 0; ti < TPB; ++ti) {
    int b = blockIdx.x * TPB + ti;
    if (b >= ntiles) break;
    int r = 0;
    while (r < 16 && Ms[T0 + r + 1] <= b) ++r;
    int tile = b - Ms[T0 + r];
    int boff = Ms[O0 + r];
    int e0 = boff + tile * 64;
    int nrows = min(64, boff + Ms[C0 + r] - e0);

    bool valid = m < nrows;
    int e = valid ? (e0 + m) : e0;
    int2 cp = sCP[e];
    if (ug == 0) {
      Pos2[0][m] = valid ? cp.y : 0;
      if (!msgmode) Rows[m] = valid ? sRow[e] : 0;
    }
    int c = cp.x;
    if (xbf) {
      const unsigned short* xr = xb + (size_t)c * 128;
      #pragma unroll
      for (int s = 0; s < 4; ++s) {
        int u = ug * 4 + s;
        short8 pk = (short8)(short)0;
        if (valid) pk = *(const short8*)(xr + u * 8);
        *(short8*)&As[(m * 17 + u) * 8] = pk;
      }
    } else {
      const float* xr = xf + (size_t)c * 128;
      #pragma unroll
      for (int s = 0; s < 4; ++s) {
        int u = ug * 4 + s;
        float4 f0 = make_float4(0.f, 0.f, 0.f, 0.f), f1 = f0;
        if (valid) {
          f0 = *(const float4*)(xr + u * 8);
          f1 = *(const float4*)(xr + u * 8 + 4);
        }
        short8 pk;
        pk[0] = (short)f2bf(f0.x); pk[1] = (short)f2bf(f0.y);
        pk[2] = (short)f2bf(f0.z); pk[3] = (short)f2bf(f0.w);
        pk[4] = (short)f2bf(f1.x); pk[5] = (short)f2bf(f1.y);
        pk[6] = (short)f2bf(f1.z); pk[7] = (short)f2bf(f1.w);
        *(short8*)&As[(m * 17 + u) * 8] = pk;
      }
    }
    __syncthreads();

    if (r != rprev) {
      const unsigned short* wr = wT + r * 16384;
      #pragma unroll
      for (int ns = 0; ns < 2; ++ns)
        #pragma unroll
        for (int kk = 0; kk < 4; ++kk)
          bfr[ns][kk] = *(const short8*)(wr + (wave * 32 + ns * 16 + l15) * 128 + kk * 32 + q * 8);
      rprev = r;
    }

    f32x4 acc[4][2];
    #pragma unroll
    for (int ms = 0; ms < 4; ++ms)
      #pragma unroll
      for (int ns = 0; ns < 2; ++ns)
        acc[ms][ns] = (f32x4){0.f, 0.f, 0.f, 0.f};
    #pragma unroll
    for (int kk = 0; kk < 4; ++kk) {
      short8 af[4];
      #pragma unroll
      for (int ms = 0; ms < 4; ++ms)
        af[ms] = *(const short8*)&As[((ms * 16 + l15) * 17 + kk * 4 + q) * 8];
      #pragma unroll
      for (int ms = 0; ms < 4; ++ms)
        #pragma unroll
        for (int ns = 0; ns < 2; ++ns)
          acc[ms][ns] = __builtin_amdgcn_mfma_f32_16x16x32_bf16(af[ms], bfr[ns][kk], acc[ms][ns], 0, 0, 0);
    }

    if (msgmode) {
      __syncthreads();
      #pragma unroll
      for (int ms = 0; ms < 4; ++ms)
        #pragma unroll
        for (int ns = 0; ns < 2; ++ns)
          #pragma unroll
          for (int reg = 0; reg < 4; ++reg)
            Es[(ms * 16 + q * 4 + reg) * 136 + wave * 32 + ns * 16 + l15] =
                (short)f2bf(acc[ms][ns][reg]);
      __syncthreads();
      #pragma unroll
      for (int i = 0; i < 4; ++i) {
        int row = wave * 16 + i * 4 + q;
        short8 v = *(const short8*)&Es[row * 136 + l15 * 8];
        if (row < nrows)
          __builtin_nontemporal_store(v,
              (short8*)(msg + (size_t)Pos2[0][row] * 128 + l15 * 8));
      }
      __syncthreads();
    } else {
      #pragma unroll
      for (int ms = 0; ms < 4; ++ms)
        #pragma unroll
        for (int reg = 0; reg < 4; ++reg) {
          int mrow = ms * 16 + q * 4 + reg;
          if (mrow < nrows) {
            float* op = out + (size_t)Rows[mrow] * 128 + wave * 32 + l15;
            unsafeAtomicAdd(op, acc[ms][0][reg]);
            unsafeAtomicAdd(op + 16, acc[ms][1][reg]);
          }
        }
      __syncthreads();
    }
  }
}

// one 16-lane group per dst (4 dsts/wave): dwordx4 row loads, fp32 accumulate, one store
// msg loads + out stores nontemporal: all stream-once traffic.
__global__ __launch_bounds__(256) void k_reduce(const unsigned short* __restrict__ msg,
    const int* __restrict__ dstOff, float* __restrict__ out)
{
  int d = blockIdx.x * 16 + (threadIdx.x >> 4);
  if (d >= NN) return;
  int sl = threadIdx.x & 15;
  int s = dstOff[d], e = dstOff[d + 1];
  const unsigned short* base = msg + (size_t)sl * 8;
  float a[8], bacc[8];
  #pragma unroll
  for (int i = 0; i < 8; ++i) { a[i] = 0.f; bacc[i] = 0.f; }
  int j = s;
  for (; j + 1 < e; j += 2) {
    u32x4 v0 = __builtin_nontemporal_load((const u32x4*)(base + (size_t)j * 128));
    u32x4 v1 = __builtin_nontemporal_load((const u32x4*)(base + (size_t)(j + 1) * 128));
    #pragma unroll
    for (int c = 0; c < 4; ++c) {
      a[2 * c]     += __builtin_bit_cast(float, v0[c] << 16);
      a[2 * c + 1] += __builtin_bit_cast(float, v0[c] & 0xffff0000u);
      bacc[2 * c]     += __builtin_bit_cast(float, v1[c] << 16);
      bacc[2 * c + 1] += __builtin_bit_cast(float, v1[c] & 0xffff0000u);
    }
  }
  if (j < e) {
    u32x4 v0 = __builtin_nontemporal_load((const u32x4*)(base + (size_t)j * 128));
    #pragma unroll
    for (int c = 0; c < 4; ++c) {
      a[2 * c]     += __builtin_bit_cast(float, v0[c] << 16);
      a[2 * c + 1] += __builtin_bit_cast(float, v0[c] & 0xffff0000u);
    }
  }
  f32x4 w0, w1;
  w0[0] = a[0] + bacc[0]; w0[1] = a[1] + bacc[1]; w0[2] = a[2] + bacc[2]; w0[3] = a[3] + bacc[3];
  w1[0] = a[4] + bacc[4]; w1[1] = a[5] + bacc[5]; w1[2] = a[6] + bacc[6]; w1[3] = a[7] + bacc[7];
  float* op = out + (size_t)d * 128 + sl * 8;
  __builtin_nontemporal_store(w0, (f32x4*)op);
  __builtin_nontemporal_store(w1, (f32x4*)(op + 4));
}

extern "C" void kernel_launch(void* const* d_in, const int* in_sizes, int n_in,
                              void* d_out, int out_size, void* d_ws, size_t ws_size,
                              hipStream_t stream)
{
  const float* x      = (const float*)d_in[0];
  const int*   ei     = (const int*)d_in[1];
  const int*   et     = (const int*)d_in[2];
  const float* bases  = (const float*)d_in[3];
  const float* coef   = (const float*)d_in[4];
  const float* w_self = (const float*)d_in[5];
  float* out = (float*)d_out;
  char* ws = (char*)d_ws;
  unsigned short* wT = (unsigned short*)(ws + WT_OFF);
  int* meta      = (int*)(ws + META_OFF);
  int* dstHist   = (int*)(ws + DH_OFF);
  int* dstOff    = (int*)(ws + DO_OFF);
  int* dstCursor = (int*)(ws + DC_OFF);
  int* blockSums = (int*)(ws + BS_OFF);
  int2* sCP      = (int2*)(ws + SCP_OFF);
  int* sRow      = (int*)(ws + SR_OFF);
  unsigned short* xb = (unsigned short*)(ws + XB_OFF);

  const int modeB = (ws_size >= NEED_B) ? 1 : 0;
  const int modeA = (modeB || ws_size >= NEED_A) ? 1 : 0;
  unsigned short* msg = (unsigned short*)(ws + (modeB ? MSGB_OFF : MSGA_OFF));

  hipMemsetAsync(ws + META_OFF, 0, 512 + 400000, stream);  // meta + dstHist
  k_prep<<<modeB ? (WGRID + 12500) : WGRID, 256, 0, stream>>>(bases, coef, w_self, wT, x, xb);
  k_hist<<<256, 256, 0, stream>>>(ei, et, meta, dstHist);
  if (modeA) {
    k_scan1<<<SCANB, 256, 0, stream>>>(dstHist, dstOff, blockSums);
    k_scan2<<<1, 512, 0, stream>>>(blockSums, meta);
    k_scan3<<<SCANB, 256, 0, stream>>>(dstOff, blockSums, dstCursor, sCP);
  } else {
    k_scan2<<<1, 512, 0, stream>>>(blockSums, meta);
    k_self0<<<SCANB, 256, 0, stream>>>(sCP, sRow);
    hipMemsetAsync(d_out, 0, (size_t)NN * D * 4, stream);
  }
  k_scatter<<<(NE + 4095) / 4096, 256, 0, stream>>>(ei, et, meta, sCP, sRow, dstCursor, modeA);
  k_gemm<<<GEMMG, 256, 0, stream>>>(x, xb, wT, meta, sCP, sRow, msg, out, modeB, modeA);
  if (modeA)
    k_reduce<<<(NN + 15) / 16, 256, 0, stream>>>(msg, dstOff, out);
}

// Round 3
// 320.220 us; speedup vs baseline: 1.0224x; 1.0009x over previous
//
#include <hip/hip_runtime.h>

#define NN 100000
#define NE 600000
#define ET (NE + NN)
#define D 128
#define NREL 16
#define SCANB 391   // 391*256 = 100096 >= NN
#define TPB 4       // tiles per gemm block
#define MAXTILES 10954
#define GEMMG ((MAXTILES + TPB - 1) / TPB)
#define WGRID 1088  // 17*16384/256

typedef short short8 __attribute__((ext_vector_type(8)));
typedef float f32x4 __attribute__((ext_vector_type(4)));
typedef unsigned int u32x4 __attribute__((ext_vector_type(4)));

// meta layout (ints)
#define C0 0    // counts[17]
#define O0 20   // offsets[18]
#define CU0 40  // cursors[17]
#define T0 60   // tileoff[18]

// ws layout (bytes)
#define WT_OFF   0                 // 17*128*128 bf16 = 557056
#define META_OFF 557056            // 512
#define DH_OFF   557568            // dstHist: 100000 ints
#define DO_OFF   957568            // dstOff: 100001 ints
#define DC_OFF   1357576           // dstCursor: 100000 ints
#define BS_OFF   1757576           // blockSums: 391 ints (pad)
#define SCP_OFF  1759576           // sCP: 700064 int2
#define SR_OFF   7360088           // sRow (fallback only): 700000 ints
#define XB_OFF   10160096          // xb: 100000*128 bf16
#define MSGB_OFF 35760096          // msg (mode B)
#define MSGA_OFF 10160096          // msg (mode A, no xb)
#define NEED_B   (MSGB_OFF + (size_t)ET * 128 * 2)
#define NEED_A   (MSGA_OFF + (size_t)ET * 128 * 2)

__device__ __forceinline__ unsigned short f2bf(float f) {
  unsigned u = __builtin_bit_cast(unsigned, f);
  u += 0x7fffu + ((u >> 16) & 1u);   // RNE; inputs finite/normal
  return (unsigned short)(u >> 16);
}

// LDS-only barrier: no vmcnt drain (prefetch regs / nt stores stay in flight).
__device__ __forceinline__ void lds_barrier() {
  asm volatile("s_waitcnt lgkmcnt(0)" ::: "memory");
  __builtin_amdgcn_s_barrier();
}

// blockIdx < WGRID: wT[r][o][i] = sum_b coef[r,b]*bases[b][i][o]; slot16 = w_self.
// else: x fp32 -> xb bf16 (4 elems/thread).
__global__ __launch_bounds__(256) void k_prep(const float* __restrict__ bases,
    const float* __restrict__ coef, const float* __restrict__ w_self,
    unsigned short* __restrict__ wT, const float* __restrict__ x,
    unsigned short* __restrict__ xb)
{
  if (blockIdx.x < WGRID) {
    int idx = blockIdx.x * 256 + threadIdx.x;   // < 17*16384
    int r = idx >> 14;
    int t = idx & 16383;
    float v;
    if (r < 16) {
      int o = t >> 7, i = t & 127;
      float acc = 0.f;
      #pragma unroll
      for (int b = 0; b < 8; ++b)
        acc += coef[r * 8 + b] * bases[b * 16384 + i * 128 + o];
      v = acc;
    } else {
      v = w_self[t];
    }
    wT[idx] = f2bf(v);
  } else {
    int i = (blockIdx.x - WGRID) * 256 + threadIdx.x;
    if (i >= NN * D / 4) return;
    // x is read exactly once per iteration -> nontemporal (keep L3 for xb/wT)
    f32x4 f = __builtin_nontemporal_load((const f32x4*)(x + (size_t)i * 4));
    unsigned short s0 = f2bf(f[0]), s1 = f2bf(f[1]), s2 = f2bf(f[2]), s3 = f2bf(f[3]);
    unsigned long long pk = (unsigned long long)s0 | ((unsigned long long)s1 << 16)
                          | ((unsigned long long)s2 << 32) | ((unsigned long long)s3 << 48);
    *(unsigned long long*)(xb + (size_t)i * 4) = pk;   // cached: xb is the reuse set
  }
}

// rel histogram (LDS) + dst histogram (global atomics)
__global__ __launch_bounds__(256) void k_hist(const int* __restrict__ ei,
    const int* __restrict__ et, int* __restrict__ meta, int* __restrict__ dstHist)
{
  __shared__ int h[16];
  int tid = threadIdx.x;
  if (tid < 16) h[tid] = 0;
  __syncthreads();
  for (int e = blockIdx.x * 256 + tid; e < NE; e += gridDim.x * 256) {
    atomicAdd(&h[et[e]], 1);
    atomicAdd(&dstHist[ei[e]], 1);
  }
  __syncthreads();
  if (tid < 16) atomicAdd(&meta[C0 + tid], h[tid]);
}

__global__ __launch_bounds__(256) void k_scan1(const int* __restrict__ dstHist,
    int* __restrict__ dstOff, int* __restrict__ blockSums)
{
  __shared__ int sh[256];
  int tid = threadIdx.x;
  int d = blockIdx.x * 256 + tid;
  int v = (d < NN) ? (dstHist[d] + 1) : 0;   // +1: virtual self edge
  sh[tid] = v;
  __syncthreads();
  #pragma unroll
  for (int ofs = 1; ofs < 256; ofs <<= 1) {
    int t = (tid >= ofs) ? sh[tid - ofs] : 0;
    __syncthreads();
    sh[tid] += t;
    __syncthreads();
  }
  if (d < NN) dstOff[d] = sh[tid] - v;
  if (tid == 255) blockSums[blockIdx.x] = sh[tid];
}

__global__ __launch_bounds__(512) void k_scan2(int* __restrict__ blockSums, int* __restrict__ meta)
{
  __shared__ int sh[SCANB];
  int tid = threadIdx.x;
  if (tid < SCANB) sh[tid] = blockSums[tid];
  __syncthreads();
  if (tid == 0) {
    int run = 0;
    for (int i = 0; i < SCANB; ++i) { int c = sh[i]; sh[i] = run; run += c; }
    meta[C0 + 16] = NN;
    int off = 0, toff = 0;
    for (int r = 0; r <= 16; ++r) {
      meta[O0 + r] = off;
      meta[CU0 + r] = off;
      meta[T0 + r] = toff;
      int c = meta[C0 + r];
      off += c;
      toff += (c + 63) >> 6;
    }
    meta[O0 + 17] = off;
    meta[T0 + 17] = toff;
  }
  __syncthreads();
  if (tid < SCANB) blockSums[tid] = sh[tid];
}

__global__ __launch_bounds__(256) void k_scan3(int* __restrict__ dstOff,
    const int* __restrict__ blockSums, int* __restrict__ dstCursor,
    int2* __restrict__ sCP)
{
  int tid = threadIdx.x;
  int d = blockIdx.x * 256 + tid;
  int base = blockSums[blockIdx.x];
  if (d < NN) {
    int o = dstOff[d] + base;
    dstOff[d] = o;
    dstCursor[d] = o + 1;
    sCP[NE + d] = make_int2(d, o);
  }
  if (d == NN) dstOff[NN] = ET;
}

__global__ __launch_bounds__(256) void k_self0(int2* __restrict__ sCP, int* __restrict__ sRow)
{
  int n = blockIdx.x * 256 + threadIdx.x;
  if (n < NN) { sCP[NE + n] = make_int2(n, 0); sRow[NE + n] = n; }
}

__global__ __launch_bounds__(256) void k_scatter(const int* __restrict__ ei, const int* __restrict__ et,
    int* __restrict__ meta, int2* __restrict__ sCP, int* __restrict__ sRow,
    int* __restrict__ dstCursor, int doMsg)
{
  __shared__ int h[16], base[16], lh[16];
  int tid = threadIdx.x;
  int start = blockIdx.x * 4096;
  int end = min(NE, start + 4096);
  if (tid < 16) { h[tid] = 0; lh[tid] = 0; }
  __syncthreads();
  for (int e = start + tid; e < end; e += 256)
    atomicAdd(&h[et[e]], 1);
  __syncthreads();
  if (tid < 16) base[tid] = atomicAdd(&meta[CU0 + tid], h[tid]);
  __syncthreads();
  for (int e = start + tid; e < end; e += 256) {
    int r = et[e];
    int row = ei[e];
    int pos = base[r] + atomicAdd(&lh[r], 1);
    int slot = doMsg ? atomicAdd(&dstCursor[row], 1) : 0;
    sCP[pos] = make_int2(ei[NE + e], slot);
    if (!doMsg) sRow[pos] = row;
  }
}

// TPB tiles/block. Fast path (xbf&&msgmode): LDS-only barriers (no vmcnt drain),
// sCP loads 2 tiles ahead, x-row gathers 1 tile ahead, bfr reload pre-bar1 —
// gathers and nt msg stores stay in flight across barriers.
// Generic fallback: R4 code (full __syncthreads, validated).
__global__ __launch_bounds__(256) void k_gemm(const float* __restrict__ xf,
    const unsigned short* __restrict__ xb,
    const unsigned short* __restrict__ wT, const int* __restrict__ meta,
    const int2* __restrict__ sCP, const int* __restrict__ sRow,
    unsigned short* __restrict__ msg, float* __restrict__ out,
    int xbf, int msgmode)
{
  __shared__ short As[64 * 17 * 8];   // staging (8704 shorts; fallback reuses for transpose)
  __shared__ short Es[64 * 136];      // epilogue rows
  __shared__ int Pos2[2][64];
  __shared__ int Rows[64];
  __shared__ int Ms[80];

  int tid = threadIdx.x;
  if (tid < 80) Ms[tid] = meta[tid];
  __syncthreads();
  int ntiles = Ms[T0 + 17];

  int lane = tid & 63, wave = tid >> 6;
  int q = lane >> 4, l15 = lane & 15;
  int m = tid >> 2, ug = tid & 3;

  if (xbf && msgmode) {
    int b0 = blockIdx.x * TPB;
    if (b0 >= ntiles) return;

    int rr = 0;   // rolling relation cursor; all tile scans are monotone in b
    // slot S: tile to stage this iter (gather data already in regs)
    short8 pfS[4]; int cyS; bool vS; int rS, nrS;
    // slot G: sCP in regs; gathers issued this iter
    int2 cpG; bool vG; int rG, nrG;
    // slot P: sCP load in flight
    int2 cpP; bool vP; int rP, nrP;

    // ---- prologue: S = tile b0 (serial sCP -> gather chain, once) ----
    {
      while (rr < 16 && Ms[T0 + rr + 1] <= b0) ++rr;
      int boff = Ms[O0 + rr];
      int e0 = boff + (b0 - Ms[T0 + rr]) * 64;
      nrS = min(64, boff + Ms[C0 + rr] - e0);
      rS = rr;
      vS = m < nrS;
      int2 cp = sCP[vS ? (e0 + m) : e0];
      cyS = cp.y;
      const unsigned short* xr = xb + (size_t)cp.x * 128;
      #pragma unroll
      for (int s = 0; s < 4; ++s) {
        short8 v = (short8)(short)0;
        if (vS) v = *(const short8*)(xr + (ug * 4 + s) * 8);
        pfS[s] = v;
      }
    }
    // ---- prologue: G = tile b0+1 (sCP only) ----
    if (TPB > 1 && b0 + 1 < ntiles) {
      int b = b0 + 1;
      while (rr < 16 && Ms[T0 + rr + 1] <= b) ++rr;
      int boff = Ms[O0 + rr];
      int e0 = boff + (b - Ms[T0 + rr]) * 64;
      nrG = min(64, boff + Ms[C0 + rr] - e0);
      rG = rr;
      vG = m < nrG;
      cpG = sCP[vG ? (e0 + m) : e0];
    } else { vG = false; nrG = 0; rG = rS; cpG = make_int2(0, 0); }

    int rprev = -1;
    short8 bfr[2][4];
    for (int ti = 0; ti < TPB; ++ti) {
      int b = b0 + ti;
      if (b >= ntiles) break;
      int curR = rS, curNr = nrS;

      // ---- 1. stage S from regs ----
      #pragma unroll
      for (int s = 0; s < 4; ++s)
        *(short8*)&As[(m * 17 + ug * 4 + s) * 8] = pfS[s];
      if (ug == 0) Pos2[ti & 1][m] = vS ? cyS : 0;

      // ---- 2. issue sCP load for tile b+2 (slot P) ----
      if (ti + 2 < TPB && b + 2 < ntiles) {
        int bp = b + 2;
        while (rr < 16 && Ms[T0 + rr + 1] <= bp) ++rr;
        int boff = Ms[O0 + rr];
        int e0 = boff + (bp - Ms[T0 + rr]) * 64;
        nrP = min(64, boff + Ms[C0 + rr] - e0);
        rP = rr;
        vP = m < nrP;
        cpP = sCP[vP ? (e0 + m) : e0];
      } else { vP = false; nrP = 0; rP = rG; cpP = make_int2(0, 0); }

      // ---- 3. issue gathers for G -> pfN (in flight across barriers) ----
      short8 pfN[4];
      {
        const unsigned short* xr = xb + (size_t)cpG.x * 128;
        #pragma unroll
        for (int s = 0; s < 4; ++s) {
          short8 v = (short8)(short)0;
          if (vG) v = *(const short8*)(xr + (ug * 4 + s) * 8);
          pfN[s] = v;
        }
      }

      // ---- 4. B frags (reload only on rel change; pre-barrier for overlap) ----
      if (curR != rprev) {
        const unsigned short* wr = wT + curR * 16384;
        #pragma unroll
        for (int ns = 0; ns < 2; ++ns)
          #pragma unroll
          for (int kk = 0; kk < 4; ++kk)
            bfr[ns][kk] = *(const short8*)(wr + (wave * 32 + ns * 16 + l15) * 128 + kk * 32 + q * 8);
        rprev = curR;
      }

      // bar1: As/Pos2 staging visible; prior Es ds_reads drained. No vmcnt drain.
      lds_barrier();

      // ---- 5. MFMA ----
      f32x4 acc[4][2];
      #pragma unroll
      for (int ms = 0; ms < 4; ++ms)
        #pragma unroll
        for (int ns = 0; ns < 2; ++ns)
          acc[ms][ns] = (f32x4){0.f, 0.f, 0.f, 0.f};
      #pragma unroll
      for (int kk = 0; kk < 4; ++kk) {
        short8 af[4];
        #pragma unroll
        for (int ms = 0; ms < 4; ++ms)
          af[ms] = *(const short8*)&As[((ms * 16 + l15) * 17 + kk * 4 + q) * 8];
        #pragma unroll
        for (int ms = 0; ms < 4; ++ms)
          #pragma unroll
          for (int ns = 0; ns < 2; ++ns)
            acc[ms][ns] = __builtin_amdgcn_mfma_f32_16x16x32_bf16(af[ms], bfr[ns][kk], acc[ms][ns], 0, 0, 0);
      }

      // ---- 6. transpose to Es ----
      #pragma unroll
      for (int ms = 0; ms < 4; ++ms)
        #pragma unroll
        for (int ns = 0; ns < 2; ++ns)
          #pragma unroll
          for (int reg = 0; reg < 4; ++reg)
            Es[(ms * 16 + q * 4 + reg) * 136 + wave * 32 + ns * 16 + l15] =
                (short)f2bf(acc[ms][ns][reg]);

      // bar2: Es visible; MFMA As-reads drained. No vmcnt drain.
      lds_barrier();

      // ---- 7. full-row msg stores (nontemporal, stay in flight) ----
      #pragma unroll
      for (int i = 0; i < 4; ++i) {
        int row = wave * 16 + i * 4 + q;
        short8 v = *(const short8*)&Es[row * 136 + l15 * 8];
        if (row < curNr)
          __builtin_nontemporal_store(v,
              (short8*)(msg + (size_t)Pos2[ti & 1][row] * 128 + l15 * 8));
      }

      // ---- 8. rotate pipeline ----
      #pragma unroll
      for (int s = 0; s < 4; ++s) pfS[s] = pfN[s];
      cyS = cpG.y; vS = vG; rS = rG; nrS = nrG;
      cpG = cpP;   vG = vP; rG = rP; nrG = nrP;
    }
    return;
  }

  // ---------------- generic fallback (R4-validated) ----------------
  int rprev = -1;
  short8 bfr[2][4];
  for (int ti = 0; ti < TPB; ++ti) {
    int b = blockIdx.x * TPB + ti;
    if (b >= ntiles) break;
    int r = 0;
    while (r < 16 && Ms[T0 + r + 1] <= b) ++r;
    int tile = b - Ms[T0 + r];
    int boff = Ms[O0 + r];
    int e0 = boff + tile * 64;
    int nrows = min(64, boff + Ms[C0 + r] - e0);

    bool valid = m < nrows;
    int e = valid ? (e0 + m) : e0;
    int2 cp = sCP[e];
    if (ug == 0) {
      Pos2[0][m] = valid ? cp.y : 0;
      if (!msgmode) Rows[m] = valid ? sRow[e] : 0;
    }
    int c = cp.x;
    if (xbf) {
      const unsigned short* xr = xb + (size_t)c * 128;
      #pragma unroll
      for (int s = 0; s < 4; ++s) {
        int u = ug * 4 + s;
        short8 pk = (short8)(short)0;
        if (valid) pk = *(const short8*)(xr + u * 8);
        *(short8*)&As[(m * 17 + u) * 8] = pk;
      }
    } else {
      const float* xr = xf + (size_t)c * 128;
      #pragma unroll
      for (int s = 0; s < 4; ++s) {
        int u = ug * 4 + s;
        float4 f0 = make_float4(0.f, 0.f, 0.f, 0.f), f1 = f0;
        if (valid) {
          f0 = *(const float4*)(xr + u * 8);
          f1 = *(const float4*)(xr + u * 8 + 4);
        }
        short8 pk;
        pk[0] = (short)f2bf(f0.x); pk[1] = (short)f2bf(f0.y);
        pk[2] = (short)f2bf(f0.z); pk[3] = (short)f2bf(f0.w);
        pk[4] = (short)f2bf(f1.x); pk[5] = (short)f2bf(f1.y);
        pk[6] = (short)f2bf(f1.z); pk[7] = (short)f2bf(f1.w);
        *(short8*)&As[(m * 17 + u) * 8] = pk;
      }
    }
    __syncthreads();

    if (r != rprev) {
      const unsigned short* wr = wT + r * 16384;
      #pragma unroll
      for (int ns = 0; ns < 2; ++ns)
        #pragma unroll
        for (int kk = 0; kk < 4; ++kk)
          bfr[ns][kk] = *(const short8*)(wr + (wave * 32 + ns * 16 + l15) * 128 + kk * 32 + q * 8);
      rprev = r;
    }

    f32x4 acc[4][2];
    #pragma unroll
    for (int ms = 0; ms < 4; ++ms)
      #pragma unroll
      for (int ns = 0; ns < 2; ++ns)
        acc[ms][ns] = (f32x4){0.f, 0.f, 0.f, 0.f};
    #pragma unroll
    for (int kk = 0; kk < 4; ++kk) {
      short8 af[4];
      #pragma unroll
      for (int ms = 0; ms < 4; ++ms)
        af[ms] = *(const short8*)&As[((ms * 16 + l15) * 17 + kk * 4 + q) * 8];
      #pragma unroll
      for (int ms = 0; ms < 4; ++ms)
        #pragma unroll
        for (int ns = 0; ns < 2; ++ns)
          acc[ms][ns] = __builtin_amdgcn_mfma_f32_16x16x32_bf16(af[ms], bfr[ns][kk], acc[ms][ns], 0, 0, 0);
    }

    if (msgmode) {
      __syncthreads();
      #pragma unroll
      for (int ms = 0; ms < 4; ++ms)
        #pragma unroll
        for (int ns = 0; ns < 2; ++ns)
          #pragma unroll
          for (int reg = 0; reg < 4; ++reg)
            Es[(ms * 16 + q * 4 + reg) * 136 + wave * 32 + ns * 16 + l15] =
                (short)f2bf(acc[ms][ns][reg]);
      __syncthreads();
      #pragma unroll
      for (int i = 0; i < 4; ++i) {
        int row = wave * 16 + i * 4 + q;
        short8 v = *(const short8*)&Es[row * 136 + l15 * 8];
        if (row < nrows)
          __builtin_nontemporal_store(v,
              (short8*)(msg + (size_t)Pos2[0][row] * 128 + l15 * 8));
      }
      __syncthreads();
    } else {
      #pragma unroll
      for (int ms = 0; ms < 4; ++ms)
        #pragma unroll
        for (int reg = 0; reg < 4; ++reg) {
          int mrow = ms * 16 + q * 4 + reg;
          if (mrow < nrows) {
            float* op = out + (size_t)Rows[mrow] * 128 + wave * 32 + l15;
            unsafeAtomicAdd(op, acc[ms][0][reg]);
            unsafeAtomicAdd(op + 16, acc[ms][1][reg]);
          }
        }
      __syncthreads();
    }
  }
}

// one 16-lane group per dst (4 dsts/wave): dwordx4 row loads, fp32 accumulate, one store
// msg loads + out stores nontemporal: all stream-once traffic.
__global__ __launch_bounds__(256) void k_reduce(const unsigned short* __restrict__ msg,
    const int* __restrict__ dstOff, float* __restrict__ out)
{
  int d = blockIdx.x * 16 + (threadIdx.x >> 4);
  if (d >= NN) return;
  int sl = threadIdx.x & 15;
  int s = dstOff[d], e = dstOff[d + 1];
  const unsigned short* base = msg + (size_t)sl * 8;
  float a[8], bacc[8];
  #pragma unroll
  for (int i = 0; i < 8; ++i) { a[i] = 0.f; bacc[i] = 0.f; }
  int j = s;
  for (; j + 1 < e; j += 2) {
    u32x4 v0 = __builtin_nontemporal_load((const u32x4*)(base + (size_t)j * 128));
    u32x4 v1 = __builtin_nontemporal_load((const u32x4*)(base + (size_t)(j + 1) * 128));
    #pragma unroll
    for (int c = 0; c < 4; ++c) {
      a[2 * c]     += __builtin_bit_cast(float, v0[c] << 16);
      a[2 * c + 1] += __builtin_bit_cast(float, v0[c] & 0xffff0000u);
      bacc[2 * c]     += __builtin_bit_cast(float, v1[c] << 16);
      bacc[2 * c + 1] += __builtin_bit_cast(float, v1[c] & 0xffff0000u);
    }
  }
  if (j < e) {
    u32x4 v0 = __builtin_nontemporal_load((const u32x4*)(base + (size_t)j * 128));
    #pragma unroll
    for (int c = 0; c < 4; ++c) {
      a[2 * c]     += __builtin_bit_cast(float, v0[c] << 16);
      a[2 * c + 1] += __builtin_bit_cast(float, v0[c] & 0xffff0000u);
    }
  }
  f32x4 w0, w1;
  w0[0] = a[0] + bacc[0]; w0[1] = a[1] + bacc[1]; w0[2] = a[2] + bacc[2]; w0[3] = a[3] + bacc[3];
  w1[0] = a[4] + bacc[4]; w1[1] = a[5] + bacc[5]; w1[2] = a[6] + bacc[6]; w1[3] = a[7] + bacc[7];
  float* op = out + (size_t)d * 128 + sl * 8;
  __builtin_nontemporal_store(w0, (f32x4*)op);
  __builtin_nontemporal_store(w1, (f32x4*)(op + 4));
}

extern "C" void kernel_launch(void* const* d_in, const int* in_sizes, int n_in,
                              void* d_out, int out_size, void* d_ws, size_t ws_size,
                              hipStream_t stream)
{
  const float* x      = (const float*)d_in[0];
  const int*   ei     = (const int*)d_in[1];
  const int*   et     = (const int*)d_in[2];
  const float* bases  = (const float*)d_in[3];
  const float* coef   = (const float*)d_in[4];
  const float* w_self = (const float*)d_in[5];
  float* out = (float*)d_out;
  char* ws = (char*)d_ws;
  unsigned short* wT = (unsigned short*)(ws + WT_OFF);
  int* meta      = (int*)(ws + META_OFF);
  int* dstHist   = (int*)(ws + DH_OFF);
  int* dstOff    = (int*)(ws + DO_OFF);
  int* dstCursor = (int*)(ws + DC_OFF);
  int* blockSums = (int*)(ws + BS_OFF);
  int2* sCP      = (int2*)(ws + SCP_OFF);
  int* sRow      = (int*)(ws + SR_OFF);
  unsigned short* xb = (unsigned short*)(ws + XB_OFF);

  const int modeB = (ws_size >= NEED_B) ? 1 : 0;
  const int modeA = (modeB || ws_size >= NEED_A) ? 1 : 0;
  unsigned short* msg = (unsigned short*)(ws + (modeB ? MSGB_OFF : MSGA_OFF));

  hipMemsetAsync(ws + META_OFF, 0, 512 + 400000, stream);  // meta + dstHist
  k_prep<<<modeB ? (WGRID + 12500) : WGRID, 256, 0, stream>>>(bases, coef, w_self, wT, x, xb);
  k_hist<<<256, 256, 0, stream>>>(ei, et, meta, dstHist);
  if (modeA) {
    k_scan1<<<SCANB, 256, 0, stream>>>(dstHist, dstOff, blockSums);
    k_scan2<<<1, 512, 0, stream>>>(blockSums, meta);
    k_scan3<<<SCANB, 256, 0, stream>>>(dstOff, blockSums, dstCursor, sCP);
  } else {
    k_scan2<<<1, 512, 0, stream>>>(blockSums, meta);
    k_self0<<<SCANB, 256, 0, stream>>>(sCP, sRow);
    hipMemsetAsync(d_out, 0, (size_t)NN * D * 4, stream);
  }
  k_scatter<<<(NE + 4095) / 4096, 256, 0, stream>>>(ei, et, meta, sCP, sRow, dstCursor, modeA);
  k_gemm<<<GEMMG, 256, 0, stream>>>(x, xb, wT, meta, sCP, sRow, msg, out, modeB, modeA);
  if (modeA)
    k_reduce<<<(NN + 15) / 16, 256, 0, stream>>>(msg, dstOff, out);
}